// Round 18
// baseline (423.070 us; speedup 1.0000x reference)
//
#include <hip/hip_runtime.h>

// HGNN layer, v18 — fp32. Top-8/lane key cache (coverage failure ~never),
// atomic-free edge gather (pairs are CSR by row), node-side CSR via scan +
// scalar-atomic transpose, fused node gather+scale. B=4, N=2304, C=64.

#define HB    4
#define HN    2304
#define HC    64
#define HK    11             // K_NEIGS + 1
#define HL    48
#define HW    22             // windows per dim
#define HE2   484            // 22*22 local edges
#define HE    (HN + HE2)
#define HRPB  4              // rows per block == waves per block
#define NSLOT 36             // keys per lane (2304/64)
#define HCAP8 512            // cache entries per row (8 u64 per lane)
#define NPAIRS (HB * HK * HN)   // sum of Dv == 11*N per batch, exact

__global__ void hg18_sentinel(float* out, int n) {
    int i = blockIdx.x * 256 + threadIdx.x;
    if (i < n) out[i] = 12345.0f;
}

__global__ void hg18_init(int* Dv, int* indeg, int* cursor, int* needfb,
                          float* bnsum, float* bnss) {
    int i = blockIdx.x * 256 + threadIdx.x;
    if (i < HB * HN) { Dv[i] = 0; indeg[i] = 0; cursor[i] = 0; needfb[i] = 0; }
    if (i < HC) { bnsum[i] = 0.f; bnss[i] = 0.f; }
}

// -------- linear h1 = x W^T + b, xsq, f32 transpose (4 rows/block) --------
__global__ __launch_bounds__(256) void hg18_linear(const float* x, const float* W,
                                                   const float* bias, float* h1,
                                                   float* xsq, float* xT) {
    int wv = threadIdx.x >> 6, lane = threadIdx.x & 63;
    int row = blockIdx.x * 4 + wv;   // 0..B*N-1
    __shared__ float xr[4][HC];
    float v = x[row * HC + lane];
    xr[wv][lane] = v;
    __syncthreads();
    float sq = v * v;
    #pragma unroll
    for (int o = 32; o > 0; o >>= 1) sq += __shfl_xor(sq, o);
    if (lane == 0) xsq[row] = sq;
    int b = row / HN, n = row % HN;
    xT[(b * HC + lane) * HN + n] = v;
    float acc = bias[lane];
    #pragma unroll 8
    for (int c = 0; c < HC; c++) acc += xr[wv][c] * W[lane * HC + c];
    h1[row * HC + lane] = acc;
}

// ======== pop machinery (v12-proven): fixed kk=11 in count ================
__device__ __forceinline__ unsigned hg18_wave_min_u32(unsigned v) {
    #pragma unroll
    for (int o = 32; o > 0; o >>= 1) {
        unsigned ov = __shfl_xor(v, o);
        v = ov < v ? ov : v;
    }
    return v;
}

#define HG18_INS4(q0, q1, q2, q3, x)                                     \
    {                                                                    \
        unsigned long long x_ = (x), n_;                                 \
        n_ = q0 < x_ ? q0 : x_; x_ = q0 < x_ ? x_ : q0; q0 = n_;         \
        n_ = q1 < x_ ? q1 : x_; x_ = q1 < x_ ? x_ : q1; q1 = n_;         \
        n_ = q2 < x_ ? q2 : x_; x_ = q2 < x_ ? x_ : q2; q2 = n_;         \
        if (x_ < q3) q3 = x_;                                            \
    }

#define HG18_CE(u, v)                                                    \
    { unsigned long long t_ = u < v ? u : v; v = u < v ? v : u; u = t_; }

#define HG18_EXTRACT(kk, EMIT)                                                     \
    {                                                                              \
        for (int j = 0; j < (kk); j++) {                                           \
            unsigned hk = (unsigned)(c0 >> 12);                                    \
            unsigned mk = hg18_wave_min_u32(hk);                                   \
            unsigned long long bal = __ballot(hk == mk);                           \
            bool iswin;                                                            \
            if (__popcll(bal) == 1) {                                              \
                iswin = (hk == mk);                                                \
            } else {                                                               \
                unsigned mc = (hk == mk) ? (unsigned)(c0 & 0xFFFu) : 0xFFFFFFFFu;  \
                unsigned mm = hg18_wave_min_u32(mc);                               \
                iswin = (mc == mm);                                                \
            }                                                                      \
            if (iswin) {                                                           \
                int bi = (int)(c0 & 0xFFFu);                                       \
                EMIT;                                                              \
                unsigned long long popped = c0;                                    \
                c0 = c1; c1 = c2; c2 = c3; c3 = CINF;                              \
                if (c0 == CINF) {                                                  \
                    _Pragma("unroll")                                              \
                    for (int s = 0; s < NSLOT; s++) {                              \
                        unsigned long long pk =                                    \
                            ((unsigned long long)key[s] << 12) |                   \
                            (unsigned)((s << 6) | lane);                           \
                        if (pk > popped) HG18_INS4(c0, c1, c2, c3, pk);            \
                    }                                                              \
                }                                                                  \
            }                                                                      \
        }                                                                          \
    }

// ======== bisection machinery (v13-proven), templated on slot count =======
template <int NS>
__device__ __forceinline__ void hg18_kth(const unsigned (&key)[NS], int kk,
                                         unsigned& T, int& cntLess, int& take) {
    unsigned andv = 0xFFFFFFFFu, orv = 0u;
    #pragma unroll
    for (int s = 0; s < NS; s++) { andv &= key[s]; orv |= key[s]; }
    #pragma unroll
    for (int o = 32; o > 0; o >>= 1) {
        andv &= (unsigned)__shfl_xor((int)andv, o);
        orv  |= (unsigned)__shfl_xor((int)orv, o);
    }
    unsigned diff = andv ^ orv;
    if (diff == 0u) { T = andv; cntLess = 0; take = kk; return; }
    int tstart = 31 - __builtin_clz(diff);
    unsigned lowmask = (tstart == 31) ? 0xFFFFFFFFu : ((1u << (tstart + 1)) - 1u);
    unsigned pref = andv & ~lowmask;
    int r = kk;
    for (int t = tstart; t >= 0; t--) {
        unsigned pt = pref >> t;
        int c = 0;
        #pragma unroll
        for (int s = 0; s < NS; s++) c += ((key[s] >> t) == pt) ? 1 : 0;
        #pragma unroll
        for (int o = 32; o > 0; o >>= 1) c += __shfl_xor(c, o);
        if (r > c) { r -= c; pref |= (1u << t); }
    }
    T = pref; cntLess = kk - r; take = r;
}

__device__ __forceinline__ void hg18_scan64(int v, int lane, int& excl, int& total) {
    int inc = v;
    #pragma unroll
    for (int o = 1; o < 64; o <<= 1) {
        int u = __shfl_up(inc, o);
        if (lane >= o) inc += u;
    }
    excl = inc - v;
    total = __shfl(inc, 63);
}

// -------- kNN count: vec distance + pop top-11 + top-8/lane cache store ---
__global__ __launch_bounds__(256) void hg18_knn_count(const float* xT, const float* xsq,
                                                      int* Dv, unsigned long long* topc) {
    __shared__ float d[HRPB][HN];                // 36 KB
    __shared__ __align__(16) float xrt[HC][HRPB];
    const int t = threadIdx.x;
    const int b = blockIdx.x / (HN / HRPB);
    const int n0 = (blockIdx.x % (HN / HRPB)) * HRPB;
    const int r = t >> 6;
    const int lane = t & 63;
    xrt[lane][r] = xT[(b * HC + lane) * HN + n0 + r];
    __syncthreads();
    float xs[HRPB];
    #pragma unroll
    for (int q = 0; q < HRPB; q++) xs[q] = xsq[b * HN + n0 + q];

    #pragma unroll
    for (int i = 0; i < 4; i++) {                // m = 0..2047, float2/thread
        const int m = 512 * i + 2 * t;
        float2 d0 = {0.f, 0.f}, d1 = {0.f, 0.f}, d2 = {0.f, 0.f}, d3 = {0.f, 0.f};
        #pragma unroll 8
        for (int c = 0; c < HC; c++) {
            float4 xq = *reinterpret_cast<const float4*>(&xrt[c][0]);
            float2 xv = *reinterpret_cast<const float2*>(&xT[(b * HC + c) * HN + m]);
            d0.x += xq.x * xv.x; d0.y += xq.x * xv.y;
            d1.x += xq.y * xv.x; d1.y += xq.y * xv.y;
            d2.x += xq.z * xv.x; d2.y += xq.z * xv.y;
            d3.x += xq.w * xv.x; d3.y += xq.w * xv.y;
        }
        float s0 = xsq[b * HN + m], s1 = xsq[b * HN + m + 1];
        *reinterpret_cast<float2*>(&d[0][m]) =
            make_float2(xs[0] + s0 - 2.f * d0.x, xs[0] + s1 - 2.f * d0.y);
        *reinterpret_cast<float2*>(&d[1][m]) =
            make_float2(xs[1] + s0 - 2.f * d1.x, xs[1] + s1 - 2.f * d1.y);
        *reinterpret_cast<float2*>(&d[2][m]) =
            make_float2(xs[2] + s0 - 2.f * d2.x, xs[2] + s1 - 2.f * d2.y);
        *reinterpret_cast<float2*>(&d[3][m]) =
            make_float2(xs[3] + s0 - 2.f * d3.x, xs[3] + s1 - 2.f * d3.y);
    }
    {                                            // scalar tail m = 2048 + t
        const int m = 2048 + t;
        float d0 = 0.f, d1 = 0.f, d2 = 0.f, d3 = 0.f;
        #pragma unroll 8
        for (int c = 0; c < HC; c++) {
            float4 xq = *reinterpret_cast<const float4*>(&xrt[c][0]);
            float xv = xT[(b * HC + c) * HN + m];
            d0 += xq.x * xv; d1 += xq.y * xv; d2 += xq.z * xv; d3 += xq.w * xv;
        }
        float sm = xsq[b * HN + m];
        d[0][m] = xs[0] + sm - 2.f * d0;
        d[1][m] = xs[1] + sm - 2.f * d1;
        d[2][m] = xs[2] + sm - 2.f * d2;
        d[3][m] = xs[3] + sm - 2.f * d3;
    }
    __syncthreads();

    const int p = n0 + r;
    const int gw = b * HN + p;
    const unsigned long long CINF = ~0ull;
    unsigned int key[NSLOT];
    unsigned long long c0, c1, c2, c3;
    #pragma unroll
    for (int s = 0; s < NSLOT; s++) {
        float f = d[r][(s << 6) | lane];
        unsigned int ub = __float_as_uint(f);
        key[s] = ub ^ (((unsigned int)(((int)ub) >> 31)) | 0x80000000u);
    }
    // top-4 build (2 chains + bitonic merge)
    {
        unsigned long long a0 = CINF, a1 = CINF, a2 = CINF, a3 = CINF;
        unsigned long long b0 = CINF, b1 = CINF, b2 = CINF, b3 = CINF;
        #pragma unroll
        for (int s = 0; s < NSLOT / 2; s++) {
            unsigned long long pa = ((unsigned long long)key[s] << 12) |
                                    (unsigned)((s << 6) | lane);
            unsigned long long pb = ((unsigned long long)key[s + 18] << 12) |
                                    (unsigned)(((s + 18) << 6) | lane);
            HG18_INS4(a0, a1, a2, a3, pa);
            HG18_INS4(b0, b1, b2, b3, pb);
        }
        c0 = a0 < b3 ? a0 : b3; c1 = a1 < b2 ? a1 : b2;
        c2 = a2 < b1 ? a2 : b1; c3 = a3 < b0 ? a3 : b0;
        HG18_CE(c0, c2); HG18_CE(c1, c3); HG18_CE(c0, c1); HG18_CE(c2, c3);
    }
    unsigned long long* tb = topc + (size_t)gw * HCAP8;
    tb[lane]       = c0;
    tb[64 + lane]  = c1;
    tb[128 + lane] = c2;
    tb[192 + lane] = c3;
    // ranks 5-8: filtered second build (strict > c3; keys distinct)
    {
        unsigned long long lo = c3;
        unsigned long long a0 = CINF, a1 = CINF, a2 = CINF, a3 = CINF;
        unsigned long long b0 = CINF, b1 = CINF, b2 = CINF, b3 = CINF;
        #pragma unroll
        for (int s = 0; s < NSLOT / 2; s++) {
            unsigned long long pa = ((unsigned long long)key[s] << 12) |
                                    (unsigned)((s << 6) | lane);
            unsigned long long pb = ((unsigned long long)key[s + 18] << 12) |
                                    (unsigned)(((s + 18) << 6) | lane);
            if (pa > lo) HG18_INS4(a0, a1, a2, a3, pa);
            if (pb > lo) HG18_INS4(b0, b1, b2, b3, pb);
        }
        unsigned long long q4 = a0 < b3 ? a0 : b3, q5 = a1 < b2 ? a1 : b2;
        unsigned long long q6 = a2 < b1 ? a2 : b1, q7 = a3 < b0 ? a3 : b0;
        HG18_CE(q4, q6); HG18_CE(q5, q7); HG18_CE(q4, q5); HG18_CE(q6, q7);
        tb[256 + lane] = q4;
        tb[320 + lane] = q5;
        tb[384 + lane] = q6;
        tb[448 + lane] = q7;
    }
    // Dv counting: pop the 11 smallest; Dv counts the popped NEIGHBOR bi
    HG18_EXTRACT(HK, atomicAdd(&Dv[b * HN + bi], 1));
}

// -------- exclusive scans (9216 = 256*36) ---------------------------------
__global__ __launch_bounds__(256) void hg18_scan(const int* v, int* out, int clamp1) {
    __shared__ int part[256];
    int t = threadIdx.x;
    int base = t * 36;
    int s = 0;
    for (int i = 0; i < 36; i++) s += clamp1 ? max(v[base + i], 1) : v[base + i];
    part[t] = s;
    __syncthreads();
    if (t == 0) { int acc = 0; for (int i = 0; i < 256; i++) { int q = part[i]; part[i] = acc; acc += q; } }
    __syncthreads();
    int acc = part[t];
    for (int i = 0; i < 36; i++) { out[base + i] = acc; acc += clamp1 ? max(v[base + i], 1) : v[base + i]; }
}

// -------- kNN select from top-8 cache, with exact coverage ballot ---------
__global__ __launch_bounds__(256) void hg18_sel_top(const unsigned long long* topc,
                                                    const int* Dv, const int* offs,
                                                    int* needfb, int* indeg,
                                                    unsigned int* pairs) {
    const int t = threadIdx.x;
    const int lane = t & 63;
    const int gw = blockIdx.x * HRPB + (t >> 6);   // global row
    const int b = gw / HN, p = gw % HN;
    const int kk = max(Dv[gw], 1);
    unsigned long long pk[8];
    unsigned key[8];
    #pragma unroll
    for (int s = 0; s < 8; s++) {
        pk[s] = topc[(size_t)gw * HCAP8 + (s << 6) + lane];
        key[s] = (unsigned)(pk[s] >> 12);
    }
    if (kk > HCAP8) {                              // cannot cover: fallback
        if (lane == 0) needfb[gw] = 1;
        return;
    }
    unsigned T; int cntLess, take;
    hg18_kth<8>(key, kk, T, cntLess, take);
    // coverage: exact iff every lane's 8th-smallest key > T
    unsigned long long bad = __ballot(key[7] <= T);
    if (bad != 0ull) {
        if (lane == 0) needfb[gw] = 1;
        return;
    }
    const int base = offs[gw];
    int cl = 0;
    #pragma unroll
    for (int s = 0; s < 8; s++) cl += (key[s] < T) ? 1 : 0;
    int off, tot;
    hg18_scan64(cl, lane, off, tot);
    int w = 0;
    #pragma unroll
    for (int s = 0; s < 8; s++) {
        if (key[s] < T) {
            int m = (int)(pk[s] & 0xFFFu);
            atomicAdd(&indeg[b * HN + m], 1);
            pairs[base + off + w] =
                ((unsigned)b << 24) | ((unsigned)p << 12) | (unsigned)m;
            w++;
        }
    }
    int lastm = -1;
    for (int t2 = 0; t2 < take; t2++) {            // ties at T: ascending m
        int mc = 0x7FFFFFFF;
        #pragma unroll
        for (int s = 0; s < 8; s++) {
            int m = (int)(pk[s] & 0xFFFu);
            if (key[s] == T && m > lastm && m < mc) mc = m;
        }
        int mmin = mc;
        #pragma unroll
        for (int o = 32; o > 0; o >>= 1) {
            int ov = __shfl_xor(mmin, o);
            mmin = ov < mmin ? ov : mmin;
        }
        if (mc == mmin) {
            atomicAdd(&indeg[b * HN + mmin], 1);
            pairs[base + cntLess + t2] =
                ((unsigned)b << 24) | ((unsigned)p << 12) | (unsigned)mmin;
        }
        lastm = mmin;
    }
}

// -------- fallback: full recompute for flagged rows (early-exit) ----------
__global__ __launch_bounds__(256) void hg18_sel_fullfb(const float* xT, const float* xsq,
                                                       const int* Dv, const int* offs,
                                                       const int* needfb, int* indeg,
                                                       unsigned int* pairs) {
    const int t = threadIdx.x;
    const int b = blockIdx.x / (HN / HRPB);
    const int n0 = (blockIdx.x % (HN / HRPB)) * HRPB;
    bool need = false;
    #pragma unroll
    for (int q = 0; q < HRPB; q++) need |= (needfb[b * HN + n0 + q] != 0);
    if (!need) return;                              // ~all blocks exit here

    __shared__ float d[HRPB][HN];
    __shared__ float xr[HRPB][HC];
    const int r = t >> 6;
    const int lane = t & 63;
    xr[r][lane] = xT[(b * HC + lane) * HN + n0 + r];
    __syncthreads();
    float xs[HRPB];
    #pragma unroll
    for (int q = 0; q < HRPB; q++) xs[q] = xsq[b * HN + n0 + q];
    for (int m = t; m < HN; m += 256) {
        float dot0 = 0.f, dot1 = 0.f, dot2 = 0.f, dot3 = 0.f;
        #pragma unroll 8
        for (int c = 0; c < HC; c++) {
            float xv = xT[(b * HC + c) * HN + m];
            dot0 += xr[0][c] * xv;
            dot1 += xr[1][c] * xv;
            dot2 += xr[2][c] * xv;
            dot3 += xr[3][c] * xv;
        }
        float xsm = xsq[b * HN + m];
        d[0][m] = xs[0] + xsm - 2.f * dot0;
        d[1][m] = xs[1] + xsm - 2.f * dot1;
        d[2][m] = xs[2] + xsm - 2.f * dot2;
        d[3][m] = xs[3] + xsm - 2.f * dot3;
    }
    __syncthreads();
    const int p = n0 + r;
    const int gw = b * HN + p;
    if (needfb[gw] == 0) return;                   // this wave's row is fine
    const int kk = max(Dv[gw], 1);
    unsigned int key[NSLOT];
    #pragma unroll
    for (int s = 0; s < NSLOT; s++) {
        float f = d[r][(s << 6) | lane];
        unsigned int ub = __float_as_uint(f);
        key[s] = ub ^ (((unsigned int)(((int)ub) >> 31)) | 0x80000000u);
    }
    unsigned T; int cntLess, take;
    hg18_kth<NSLOT>(key, kk, T, cntLess, take);
    const int base = offs[gw];
    int cl = 0;
    #pragma unroll
    for (int s = 0; s < NSLOT; s++) cl += (key[s] < T) ? 1 : 0;
    int off, tot;
    hg18_scan64(cl, lane, off, tot);
    int w = 0;
    #pragma unroll
    for (int s = 0; s < NSLOT; s++) {
        if (key[s] < T) {
            int m = (s << 6) | lane;
            atomicAdd(&indeg[b * HN + m], 1);
            pairs[base + off + w] =
                ((unsigned)b << 24) | ((unsigned)p << 12) | (unsigned)m;
            w++;
        }
    }
    int lastm = -1;
    for (int t2 = 0; t2 < take; t2++) {
        int mc = 0x7FFFFFFF;
        #pragma unroll
        for (int s = 0; s < NSLOT; s++) {
            int m = (s << 6) | lane;
            if (key[s] == T && m > lastm && m < mc) mc = m;
        }
        int mmin = mc;
        #pragma unroll
        for (int o = 32; o > 0; o >>= 1) {
            int ov = __shfl_xor(mmin, o);
            mmin = ov < mmin ? ov : mmin;
        }
        if (mc == mmin) {
            atomicAdd(&indeg[b * HN + mmin], 1);
            pairs[base + cntLess + t2] =
                ((unsigned)b << 24) | ((unsigned)p << 12) | (unsigned)mmin;
        }
        lastm = mmin;
    }
}

// -------- CSR transpose: pair -> per-node incoming list (scalar atomics) --
__global__ __launch_bounds__(256) void hg18_transpose(const unsigned int* pairs,
                                                      const int* moffs, int* cursor,
                                                      unsigned short* inlist) {
    int idx = blockIdx.x * 256 + threadIdx.x;
    if (idx >= NPAIRS) return;
    unsigned pk = pairs[idx];
    int b = pk >> 24;
    if (b >= HB) return;                           // defensive (poison)
    int p = (pk >> 12) & 0xFFF, m = pk & 0xFFF;
    int g = b * HN + m;
    int slot = atomicAdd(&cursor[g], 1);
    inlist[moffs[g] + slot] = (unsigned short)p;
}

__device__ __forceinline__ int hg18_lo(int rc) { return max(0, (rc - 3) / 2); }
__device__ __forceinline__ int hg18_hi(int rc) { return min(HW - 1, rc / 2); }

// -------- prep: h1 *= Dv^-1/2 (no zeroing needed anymore) -----------------
__global__ __launch_bounds__(256) void hg18_prep(float* h1, const int* indeg) {
    int i = blockIdx.x * 256 + threadIdx.x;      // over B*N*C
    int node = i >> 6;
    int n = node % HN;
    int r = n / HL, c = n % HL;
    int cover = max(0, hg18_hi(r) - hg18_lo(r) + 1) * max(0, hg18_hi(c) - hg18_lo(c) + 1);
    int dvn = max(indeg[node] + cover, 1);
    h1[i] *= rsqrtf((float)dvn);
}

// -------- edge gather: z[e] = (1/DE) sum members (no atomics) -------------
__global__ __launch_bounds__(256) void hg18_edge(const unsigned int* pairs, const int* Dv,
                                                 const int* offs, const float* y, float* z) {
    int wv = (blockIdx.x * 256 + threadIdx.x) >> 6;    // one wave per (b, edge)
    int lane = threadIdx.x & 63;
    int b = wv / HE, e = wv % HE;
    float acc = 0.f;
    if (e < HN) {
        int gw = b * HN + e;
        int kk = max(Dv[gw], 1);
        int base = offs[gw];
        for (int j0 = 0; j0 < kk; j0 += 64) {
            unsigned pk = (j0 + lane < kk) ? pairs[base + j0 + lane] : 0u;
            int lim = min(64, kk - j0);
            for (int j = 0; j < lim; j++) {
                int m = (int)(__shfl(pk, j) & 0xFFFu);
                acc += y[(b * HN + m) * HC + lane];
            }
        }
        acc *= 1.f / (float)kk;
    } else {
        int w = e - HN; int wr = w / HW, wc = w % HW;
        #pragma unroll
        for (int i = 0; i < 5; i++)
            #pragma unroll
            for (int j = 0; j < 5; j++)
                acc += y[(b * HN + (wr * 2 + i) * HL + wc * 2 + j) * HC + lane];
        acc *= (1.f / 25.f);
    }
    z[(b * HE + e) * HC + lane] = acc;
}

// -------- node gather + windows + final Dv^-1/2 scale (no atomics) --------
__global__ __launch_bounds__(256) void hg18_node(const float* z, const int* indeg,
                                                 const int* moffs, const unsigned short* inlist,
                                                 float* h2) {
    int wv = (blockIdx.x * 256 + threadIdx.x) >> 6;    // one wave per (b, node)
    int lane = threadIdx.x & 63;
    int b = wv / HN, n = wv % HN;
    int g = b * HN + n;
    int cnt = indeg[g], off = moffs[g];
    float acc = 0.f;
    for (int j0 = 0; j0 < cnt; j0 += 64) {
        int pv = (j0 + lane < cnt) ? (int)inlist[off + j0 + lane] : 0;
        int lim = min(64, cnt - j0);
        for (int j = 0; j < lim; j++) {
            int p = __shfl(pv, j);
            acc += z[(b * HE + p) * HC + lane];
        }
    }
    int r = n / HL, c = n % HL;
    int rlo = hg18_lo(r), rhi = hg18_hi(r), clo = hg18_lo(c), chi = hg18_hi(c);
    for (int wr = rlo; wr <= rhi; wr++)
        for (int wc = clo; wc <= chi; wc++)
            acc += z[(b * HE + HN + wr * HW + wc) * HC + lane];
    int dvn = max(cnt + max(0, rhi - rlo + 1) * max(0, chi - clo + 1), 1);
    h2[g * HC + lane] = acc * rsqrtf((float)dvn);
}

// -------- BN stats --------------------------------------------------------
__global__ __launch_bounds__(256) void hg18_bnstats(const float* h2, float* bnsum, float* bnss) {
    int t = threadIdx.x;
    int c = t & 63, rg = t >> 6;
    int row0 = blockIdx.x * 36;      // 256 blocks * 36 rows = 9216
    float s = 0.f, ss = 0.f;
    for (int r = rg; r < 36; r += 4) {
        float v = h2[(row0 + r) * HC + c];
        s += v; ss += v * v;
    }
    __shared__ float ls[256], lss[256];
    ls[t] = s; lss[t] = ss;
    __syncthreads();
    if (t < 64) {
        s  = ls[t]  + ls[t + 64]  + ls[t + 128]  + ls[t + 192];
        ss = lss[t] + lss[t + 64] + lss[t + 128] + lss[t + 192];
        atomicAdd(&bnsum[t], s);
        atomicAdd(&bnss[t], ss);
    }
}

// -------- BN + ReLU + residual --------------------------------------------
__global__ __launch_bounds__(256) void hg18_final(const float* h2, const float* x,
                                                  const float* gamma, const float* beta,
                                                  const float* bnsum, const float* bnss,
                                                  float* out) {
    int i = blockIdx.x * 256 + threadIdx.x;
    int c = i & 63;
    const float M = (float)(HB * HN);
    float mean = bnsum[c] / M;
    float var  = bnss[c] / M - mean * mean;
    float inv  = rsqrtf(var + 1e-5f);
    float h = gamma[c] * (h2[i] - mean) * inv + beta[c];
    out[i] = fmaxf(h, 0.f) + x[i];
}

extern "C" void kernel_launch(void* const* d_in, const int* in_sizes, int n_in,
                              void* d_out, int out_size, void* d_ws, size_t ws_size,
                              hipStream_t stream) {
    const float* x     = (const float*)d_in[0];
    const float* W     = (const float*)d_in[1];
    const float* bias  = (const float*)d_in[2];
    const float* gamma = (const float*)d_in[3];
    const float* beta  = (const float*)d_in[4];
    float* out = (float*)d_out;
    (void)in_sizes; (void)n_in;

    char* ws = (char*)d_ws;
    size_t off = 0;
    float*              xsq    = (float*)(ws + off);              off += (size_t)HB * HN * 4;
    float*              h1     = (float*)(ws + off);              off += (size_t)HB * HN * HC * 4;
    float*              h2     = (float*)(ws + off);              off += (size_t)HB * HN * HC * 4;
    int*                Dv     = (int*)(ws + off);                off += (size_t)HB * HN * 4;
    int*                indeg  = (int*)(ws + off);                off += (size_t)HB * HN * 4;
    int*                offs   = (int*)(ws + off);                off += (size_t)HB * HN * 4;
    int*                moffs  = (int*)(ws + off);                off += (size_t)HB * HN * 4;
    int*                cursor = (int*)(ws + off);                off += (size_t)HB * HN * 4;
    int*                needfb = (int*)(ws + off);                off += (size_t)HB * HN * 4;
    unsigned int*       pairs  = (unsigned int*)(ws + off);       off += (size_t)NPAIRS * 4;
    unsigned short*     inlist = (unsigned short*)(ws + off);     off += (size_t)NPAIRS * 2;
    float*              bnsum  = (float*)(ws + off);              off += 256;
    float*              bnss   = (float*)(ws + off);              off += 256;
    unsigned long long* topc   = (unsigned long long*)(ws + off); off += (size_t)HB * HN * HCAP8 * 8;
    float*              xT     = (float*)(ws + off);              // z aliases xT
    float*              z      = (float*)(ws + off);
    off += (size_t)HB * HE * HC * 4;   // max(xT, z) = z

    if (ws_size < off) {
        hg18_sentinel<<<(out_size + 255) / 256, 256, 0, stream>>>(out, out_size);
        return;
    }

    hg18_init<<<(HB * HN + 255) / 256, 256, 0, stream>>>(Dv, indeg, cursor, needfb, bnsum, bnss);
    hg18_linear<<<HB * HN / 4, 256, 0, stream>>>(x, W, bias, h1, xsq, xT);
    hg18_knn_count<<<HB * (HN / HRPB), 256, 0, stream>>>(xT, xsq, Dv, topc);
    hg18_scan<<<1, 256, 0, stream>>>(Dv, offs, 1);
    hg18_sel_top<<<HB * (HN / HRPB), 256, 0, stream>>>(topc, Dv, offs, needfb, indeg, pairs);
    hg18_sel_fullfb<<<HB * (HN / HRPB), 256, 0, stream>>>(xT, xsq, Dv, offs, needfb, indeg, pairs);
    hg18_scan<<<1, 256, 0, stream>>>(indeg, moffs, 0);
    hg18_transpose<<<(NPAIRS + 255) / 256, 256, 0, stream>>>(pairs, moffs, cursor, inlist);
    hg18_prep<<<(HB * HN * HC) / 256, 256, 0, stream>>>(h1, indeg);
    hg18_edge<<<(HB * HE) / 4, 256, 0, stream>>>(pairs, Dv, offs, h1, z);
    hg18_node<<<(HB * HN) / 4, 256, 0, stream>>>(z, indeg, moffs, inlist, h2);
    hg18_bnstats<<<256, 256, 0, stream>>>(h2, bnsum, bnss);
    hg18_final<<<(HB * HN * HC) / 256, 256, 0, stream>>>(h2, x, gamma, beta, bnsum, bnss, out);
}

// Round 19
// 388.957 us; speedup vs baseline: 1.0877x; 1.0877x over previous
//
#include <hip/hip_runtime.h>

// HGNN layer, v19 — fp32. v17 pipeline (atomic edge/gscatter/gfinish — the
// gather variant in v18 regressed: serial shfl+load chains lose to pipelined
// fire-and-forget atomics) with v18's top-8/lane cache so the coverage
// ballot ~never fails and sel_fullfb is a pure guard. B=4, N=2304, C=64.

#define HB    4
#define HN    2304
#define HC    64
#define HK    11             // K_NEIGS + 1
#define HL    48
#define HW    22             // windows per dim
#define HE2   484            // 22*22 local edges
#define HE    (HN + HE2)
#define HRPB  4              // rows per block == waves per block
#define NSLOT 36             // keys per lane (2304/64)
#define HCAP8 512            // cache entries per row (8 u64 per lane)
#define NPAIRS (HB * HK * HN)   // sum of Dv == 11*N per batch, exact

__global__ void hg19_sentinel(float* out, int n) {
    int i = blockIdx.x * 256 + threadIdx.x;
    if (i < n) out[i] = 12345.0f;
}

__global__ void hg19_init(int* Dv, int* indeg, int* needfb, float* bnsum, float* bnss) {
    int i = blockIdx.x * 256 + threadIdx.x;
    if (i < HB * HN) { Dv[i] = 0; indeg[i] = 0; needfb[i] = 0; }
    if (i < HC) { bnsum[i] = 0.f; bnss[i] = 0.f; }
}

// -------- linear h1 = x W^T + b, xsq, f32 transpose (4 rows/block) --------
__global__ __launch_bounds__(256) void hg19_linear(const float* x, const float* W,
                                                   const float* bias, float* h1,
                                                   float* xsq, float* xT) {
    int wv = threadIdx.x >> 6, lane = threadIdx.x & 63;
    int row = blockIdx.x * 4 + wv;   // 0..B*N-1
    __shared__ float xr[4][HC];
    float v = x[row * HC + lane];
    xr[wv][lane] = v;
    __syncthreads();
    float sq = v * v;
    #pragma unroll
    for (int o = 32; o > 0; o >>= 1) sq += __shfl_xor(sq, o);
    if (lane == 0) xsq[row] = sq;
    int b = row / HN, n = row % HN;
    xT[(b * HC + lane) * HN + n] = v;
    float acc = bias[lane];
    #pragma unroll 8
    for (int c = 0; c < HC; c++) acc += xr[wv][c] * W[lane * HC + c];
    h1[row * HC + lane] = acc;
}

// ======== pop machinery (v12-proven): fixed kk=11 in count ================
__device__ __forceinline__ unsigned hg19_wave_min_u32(unsigned v) {
    #pragma unroll
    for (int o = 32; o > 0; o >>= 1) {
        unsigned ov = __shfl_xor(v, o);
        v = ov < v ? ov : v;
    }
    return v;
}

#define HG19_INS4(q0, q1, q2, q3, x)                                     \
    {                                                                    \
        unsigned long long x_ = (x), n_;                                 \
        n_ = q0 < x_ ? q0 : x_; x_ = q0 < x_ ? x_ : q0; q0 = n_;         \
        n_ = q1 < x_ ? q1 : x_; x_ = q1 < x_ ? x_ : q1; q1 = n_;         \
        n_ = q2 < x_ ? q2 : x_; x_ = q2 < x_ ? x_ : q2; q2 = n_;         \
        if (x_ < q3) q3 = x_;                                            \
    }

#define HG19_CE(u, v)                                                    \
    { unsigned long long t_ = u < v ? u : v; v = u < v ? v : u; u = t_; }

#define HG19_EXTRACT(kk, EMIT)                                                     \
    {                                                                              \
        for (int j = 0; j < (kk); j++) {                                           \
            unsigned hk = (unsigned)(c0 >> 12);                                    \
            unsigned mk = hg19_wave_min_u32(hk);                                   \
            unsigned long long bal = __ballot(hk == mk);                           \
            bool iswin;                                                            \
            if (__popcll(bal) == 1) {                                              \
                iswin = (hk == mk);                                                \
            } else {                                                               \
                unsigned mc = (hk == mk) ? (unsigned)(c0 & 0xFFFu) : 0xFFFFFFFFu;  \
                unsigned mm = hg19_wave_min_u32(mc);                               \
                iswin = (mc == mm);                                                \
            }                                                                      \
            if (iswin) {                                                           \
                int bi = (int)(c0 & 0xFFFu);                                       \
                EMIT;                                                              \
                unsigned long long popped = c0;                                    \
                c0 = c1; c1 = c2; c2 = c3; c3 = CINF;                              \
                if (c0 == CINF) {                                                  \
                    _Pragma("unroll")                                              \
                    for (int s = 0; s < NSLOT; s++) {                              \
                        unsigned long long pk =                                    \
                            ((unsigned long long)key[s] << 12) |                   \
                            (unsigned)((s << 6) | lane);                           \
                        if (pk > popped) HG19_INS4(c0, c1, c2, c3, pk);            \
                    }                                                              \
                }                                                                  \
            }                                                                      \
        }                                                                          \
    }

// ======== bisection machinery (v13-proven), templated on slot count =======
template <int NS>
__device__ __forceinline__ void hg19_kth(const unsigned (&key)[NS], int kk,
                                         unsigned& T, int& cntLess, int& take) {
    unsigned andv = 0xFFFFFFFFu, orv = 0u;
    #pragma unroll
    for (int s = 0; s < NS; s++) { andv &= key[s]; orv |= key[s]; }
    #pragma unroll
    for (int o = 32; o > 0; o >>= 1) {
        andv &= (unsigned)__shfl_xor((int)andv, o);
        orv  |= (unsigned)__shfl_xor((int)orv, o);
    }
    unsigned diff = andv ^ orv;
    if (diff == 0u) { T = andv; cntLess = 0; take = kk; return; }
    int tstart = 31 - __builtin_clz(diff);
    unsigned lowmask = (tstart == 31) ? 0xFFFFFFFFu : ((1u << (tstart + 1)) - 1u);
    unsigned pref = andv & ~lowmask;
    int r = kk;
    for (int t = tstart; t >= 0; t--) {
        unsigned pt = pref >> t;
        int c = 0;
        #pragma unroll
        for (int s = 0; s < NS; s++) c += ((key[s] >> t) == pt) ? 1 : 0;
        #pragma unroll
        for (int o = 32; o > 0; o >>= 1) c += __shfl_xor(c, o);
        if (r > c) { r -= c; pref |= (1u << t); }
    }
    T = pref; cntLess = kk - r; take = r;
}

__device__ __forceinline__ void hg19_scan64(int v, int lane, int& excl, int& total) {
    int inc = v;
    #pragma unroll
    for (int o = 1; o < 64; o <<= 1) {
        int u = __shfl_up(inc, o);
        if (lane >= o) inc += u;
    }
    excl = inc - v;
    total = __shfl(inc, 63);
}

// -------- kNN count: vec distance + pop top-11 + top-8/lane cache store ---
__global__ __launch_bounds__(256) void hg19_knn_count(const float* xT, const float* xsq,
                                                      int* Dv, unsigned long long* topc) {
    __shared__ float d[HRPB][HN];                // 36 KB
    __shared__ __align__(16) float xrt[HC][HRPB];
    const int t = threadIdx.x;
    const int b = blockIdx.x / (HN / HRPB);
    const int n0 = (blockIdx.x % (HN / HRPB)) * HRPB;
    const int r = t >> 6;
    const int lane = t & 63;
    xrt[lane][r] = xT[(b * HC + lane) * HN + n0 + r];
    __syncthreads();
    float xs[HRPB];
    #pragma unroll
    for (int q = 0; q < HRPB; q++) xs[q] = xsq[b * HN + n0 + q];

    #pragma unroll
    for (int i = 0; i < 4; i++) {                // m = 0..2047, float2/thread
        const int m = 512 * i + 2 * t;
        float2 d0 = {0.f, 0.f}, d1 = {0.f, 0.f}, d2 = {0.f, 0.f}, d3 = {0.f, 0.f};
        #pragma unroll 8
        for (int c = 0; c < HC; c++) {
            float4 xq = *reinterpret_cast<const float4*>(&xrt[c][0]);
            float2 xv = *reinterpret_cast<const float2*>(&xT[(b * HC + c) * HN + m]);
            d0.x += xq.x * xv.x; d0.y += xq.x * xv.y;
            d1.x += xq.y * xv.x; d1.y += xq.y * xv.y;
            d2.x += xq.z * xv.x; d2.y += xq.z * xv.y;
            d3.x += xq.w * xv.x; d3.y += xq.w * xv.y;
        }
        float s0 = xsq[b * HN + m], s1 = xsq[b * HN + m + 1];
        *reinterpret_cast<float2*>(&d[0][m]) =
            make_float2(xs[0] + s0 - 2.f * d0.x, xs[0] + s1 - 2.f * d0.y);
        *reinterpret_cast<float2*>(&d[1][m]) =
            make_float2(xs[1] + s0 - 2.f * d1.x, xs[1] + s1 - 2.f * d1.y);
        *reinterpret_cast<float2*>(&d[2][m]) =
            make_float2(xs[2] + s0 - 2.f * d2.x, xs[2] + s1 - 2.f * d2.y);
        *reinterpret_cast<float2*>(&d[3][m]) =
            make_float2(xs[3] + s0 - 2.f * d3.x, xs[3] + s1 - 2.f * d3.y);
    }
    {                                            // scalar tail m = 2048 + t
        const int m = 2048 + t;
        float d0 = 0.f, d1 = 0.f, d2 = 0.f, d3 = 0.f;
        #pragma unroll 8
        for (int c = 0; c < HC; c++) {
            float4 xq = *reinterpret_cast<const float4*>(&xrt[c][0]);
            float xv = xT[(b * HC + c) * HN + m];
            d0 += xq.x * xv; d1 += xq.y * xv; d2 += xq.z * xv; d3 += xq.w * xv;
        }
        float sm = xsq[b * HN + m];
        d[0][m] = xs[0] + sm - 2.f * d0;
        d[1][m] = xs[1] + sm - 2.f * d1;
        d[2][m] = xs[2] + sm - 2.f * d2;
        d[3][m] = xs[3] + sm - 2.f * d3;
    }
    __syncthreads();

    const int p = n0 + r;
    const int gw = b * HN + p;
    const unsigned long long CINF = ~0ull;
    unsigned int key[NSLOT];
    unsigned long long c0, c1, c2, c3;
    #pragma unroll
    for (int s = 0; s < NSLOT; s++) {
        float f = d[r][(s << 6) | lane];
        unsigned int ub = __float_as_uint(f);
        key[s] = ub ^ (((unsigned int)(((int)ub) >> 31)) | 0x80000000u);
    }
    // top-4 build (2 chains + bitonic merge)
    {
        unsigned long long a0 = CINF, a1 = CINF, a2 = CINF, a3 = CINF;
        unsigned long long b0 = CINF, b1 = CINF, b2 = CINF, b3 = CINF;
        #pragma unroll
        for (int s = 0; s < NSLOT / 2; s++) {
            unsigned long long pa = ((unsigned long long)key[s] << 12) |
                                    (unsigned)((s << 6) | lane);
            unsigned long long pb = ((unsigned long long)key[s + 18] << 12) |
                                    (unsigned)(((s + 18) << 6) | lane);
            HG19_INS4(a0, a1, a2, a3, pa);
            HG19_INS4(b0, b1, b2, b3, pb);
        }
        c0 = a0 < b3 ? a0 : b3; c1 = a1 < b2 ? a1 : b2;
        c2 = a2 < b1 ? a2 : b1; c3 = a3 < b0 ? a3 : b0;
        HG19_CE(c0, c2); HG19_CE(c1, c3); HG19_CE(c0, c1); HG19_CE(c2, c3);
    }
    unsigned long long* tb = topc + (size_t)gw * HCAP8;
    tb[lane]       = c0;
    tb[64 + lane]  = c1;
    tb[128 + lane] = c2;
    tb[192 + lane] = c3;
    // ranks 5-8: filtered second build (strict > c3; packed keys distinct)
    {
        unsigned long long lo = c3;
        unsigned long long a0 = CINF, a1 = CINF, a2 = CINF, a3 = CINF;
        unsigned long long b0 = CINF, b1 = CINF, b2 = CINF, b3 = CINF;
        #pragma unroll
        for (int s = 0; s < NSLOT / 2; s++) {
            unsigned long long pa = ((unsigned long long)key[s] << 12) |
                                    (unsigned)((s << 6) | lane);
            unsigned long long pb = ((unsigned long long)key[s + 18] << 12) |
                                    (unsigned)(((s + 18) << 6) | lane);
            if (pa > lo) HG19_INS4(a0, a1, a2, a3, pa);
            if (pb > lo) HG19_INS4(b0, b1, b2, b3, pb);
        }
        unsigned long long q4 = a0 < b3 ? a0 : b3, q5 = a1 < b2 ? a1 : b2;
        unsigned long long q6 = a2 < b1 ? a2 : b1, q7 = a3 < b0 ? a3 : b0;
        HG19_CE(q4, q6); HG19_CE(q5, q7); HG19_CE(q4, q5); HG19_CE(q6, q7);
        tb[256 + lane] = q4;
        tb[320 + lane] = q5;
        tb[384 + lane] = q6;
        tb[448 + lane] = q7;
    }
    // Dv counting: pop the 11 smallest; Dv counts the popped NEIGHBOR bi
    HG19_EXTRACT(HK, atomicAdd(&Dv[b * HN + bi], 1));
}

// -------- exclusive scan of Dv (9216 = 256*36) into offs ------------------
__global__ __launch_bounds__(256) void hg19_scan(const int* Dv, int* offs) {
    __shared__ int part[256];
    int t = threadIdx.x;
    int base = t * 36;
    int s = 0;
    for (int i = 0; i < 36; i++) s += max(Dv[base + i], 1);
    part[t] = s;
    __syncthreads();
    if (t == 0) { int acc = 0; for (int i = 0; i < 256; i++) { int v = part[i]; part[i] = acc; acc += v; } }
    __syncthreads();
    int acc = part[t];
    for (int i = 0; i < 36; i++) { offs[base + i] = acc; acc += max(Dv[base + i], 1); }
}

// -------- kNN select from top-8 cache, with exact coverage ballot ---------
__global__ __launch_bounds__(256) void hg19_sel_top(const unsigned long long* topc,
                                                    const int* Dv, const int* offs,
                                                    int* needfb, int* indeg,
                                                    unsigned int* pairs) {
    const int t = threadIdx.x;
    const int lane = t & 63;
    const int gw = blockIdx.x * HRPB + (t >> 6);   // global row
    const int b = gw / HN, p = gw % HN;
    const int kk = max(Dv[gw], 1);
    unsigned long long pk[8];
    unsigned key[8];
    #pragma unroll
    for (int s = 0; s < 8; s++) {
        pk[s] = topc[(size_t)gw * HCAP8 + (s << 6) + lane];
        key[s] = (unsigned)(pk[s] >> 12);
    }
    if (kk > HCAP8) {                              // cannot cover: fallback
        if (lane == 0) needfb[gw] = 1;
        return;
    }
    unsigned T; int cntLess, take;
    hg19_kth<8>(key, kk, T, cntLess, take);
    // coverage: exact iff every lane's 8th-smallest key > T
    unsigned long long bad = __ballot(key[7] <= T);
    if (bad != 0ull) {
        if (lane == 0) needfb[gw] = 1;
        return;
    }
    const int base = offs[gw];
    int cl = 0;
    #pragma unroll
    for (int s = 0; s < 8; s++) cl += (key[s] < T) ? 1 : 0;
    int off, tot;
    hg19_scan64(cl, lane, off, tot);
    int w = 0;
    #pragma unroll
    for (int s = 0; s < 8; s++) {
        if (key[s] < T) {
            int m = (int)(pk[s] & 0xFFFu);
            atomicAdd(&indeg[b * HN + m], 1);
            pairs[base + off + w] =
                ((unsigned)b << 24) | ((unsigned)p << 12) | (unsigned)m;
            w++;
        }
    }
    int lastm = -1;
    for (int t2 = 0; t2 < take; t2++) {            // ties at T: ascending m
        int mc = 0x7FFFFFFF;
        #pragma unroll
        for (int s = 0; s < 8; s++) {
            int m = (int)(pk[s] & 0xFFFu);
            if (key[s] == T && m > lastm && m < mc) mc = m;
        }
        int mmin = mc;
        #pragma unroll
        for (int o = 32; o > 0; o >>= 1) {
            int ov = __shfl_xor(mmin, o);
            mmin = ov < mmin ? ov : mmin;
        }
        if (mc == mmin) {
            atomicAdd(&indeg[b * HN + mmin], 1);
            pairs[base + cntLess + t2] =
                ((unsigned)b << 24) | ((unsigned)p << 12) | (unsigned)mmin;
        }
        lastm = mmin;
    }
}

// -------- fallback: full recompute for flagged rows (early-exit) ----------
__global__ __launch_bounds__(256) void hg19_sel_fullfb(const float* xT, const float* xsq,
                                                       const int* Dv, const int* offs,
                                                       const int* needfb, int* indeg,
                                                       unsigned int* pairs) {
    const int t = threadIdx.x;
    const int b = blockIdx.x / (HN / HRPB);
    const int n0 = (blockIdx.x % (HN / HRPB)) * HRPB;
    bool need = false;
    #pragma unroll
    for (int q = 0; q < HRPB; q++) need |= (needfb[b * HN + n0 + q] != 0);
    if (!need) return;                              // ~all blocks exit here

    __shared__ float d[HRPB][HN];
    __shared__ float xr[HRPB][HC];
    const int r = t >> 6;
    const int lane = t & 63;
    xr[r][lane] = xT[(b * HC + lane) * HN + n0 + r];
    __syncthreads();
    float xs[HRPB];
    #pragma unroll
    for (int q = 0; q < HRPB; q++) xs[q] = xsq[b * HN + n0 + q];
    for (int m = t; m < HN; m += 256) {
        float dot0 = 0.f, dot1 = 0.f, dot2 = 0.f, dot3 = 0.f;
        #pragma unroll 8
        for (int c = 0; c < HC; c++) {
            float xv = xT[(b * HC + c) * HN + m];
            dot0 += xr[0][c] * xv;
            dot1 += xr[1][c] * xv;
            dot2 += xr[2][c] * xv;
            dot3 += xr[3][c] * xv;
        }
        float xsm = xsq[b * HN + m];
        d[0][m] = xs[0] + xsm - 2.f * dot0;
        d[1][m] = xs[1] + xsm - 2.f * dot1;
        d[2][m] = xs[2] + xsm - 2.f * dot2;
        d[3][m] = xs[3] + xsm - 2.f * dot3;
    }
    __syncthreads();
    const int p = n0 + r;
    const int gw = b * HN + p;
    if (needfb[gw] == 0) return;                   // this wave's row is fine
    const int kk = max(Dv[gw], 1);
    unsigned int key[NSLOT];
    #pragma unroll
    for (int s = 0; s < NSLOT; s++) {
        float f = d[r][(s << 6) | lane];
        unsigned int ub = __float_as_uint(f);
        key[s] = ub ^ (((unsigned int)(((int)ub) >> 31)) | 0x80000000u);
    }
    unsigned T; int cntLess, take;
    hg19_kth<NSLOT>(key, kk, T, cntLess, take);
    const int base = offs[gw];
    int cl = 0;
    #pragma unroll
    for (int s = 0; s < NSLOT; s++) cl += (key[s] < T) ? 1 : 0;
    int off, tot;
    hg19_scan64(cl, lane, off, tot);
    int w = 0;
    #pragma unroll
    for (int s = 0; s < NSLOT; s++) {
        if (key[s] < T) {
            int m = (s << 6) | lane;
            atomicAdd(&indeg[b * HN + m], 1);
            pairs[base + off + w] =
                ((unsigned)b << 24) | ((unsigned)p << 12) | (unsigned)m;
            w++;
        }
    }
    int lastm = -1;
    for (int t2 = 0; t2 < take; t2++) {
        int mc = 0x7FFFFFFF;
        #pragma unroll
        for (int s = 0; s < NSLOT; s++) {
            int m = (s << 6) | lane;
            if (key[s] == T && m > lastm && m < mc) mc = m;
        }
        int mmin = mc;
        #pragma unroll
        for (int o = 32; o > 0; o >>= 1) {
            int ov = __shfl_xor(mmin, o);
            mmin = ov < mmin ? ov : mmin;
        }
        if (mc == mmin) {
            atomicAdd(&indeg[b * HN + mmin], 1);
            pairs[base + cntLess + t2] =
                ((unsigned)b << 24) | ((unsigned)p << 12) | (unsigned)mmin;
        }
        lastm = mmin;
    }
}

__device__ __forceinline__ int hg19_lo(int rc) { return max(0, (rc - 3) / 2); }
__device__ __forceinline__ int hg19_hi(int rc) { return min(HW - 1, rc / 2); }

// -------- fused prep: h1 *= Dv^-1/2 ; z = 0 ; h2 = 0 ----------------------
__global__ __launch_bounds__(256) void hg19_prep(float* h1, const int* indeg,
                                                 float* z, float* h2) {
    int i = blockIdx.x * 256 + threadIdx.x;      // over B*N*C
    int node = i >> 6;
    int n = node % HN;
    int r = n / HL, c = n % HL;
    int cover = max(0, hg19_hi(r) - hg19_lo(r) + 1) * max(0, hg19_hi(c) - hg19_lo(c) + 1);
    int dvn = max(indeg[node] + cover, 1);
    h1[i] *= rsqrtf((float)dvn);
    int b = i / (HN * HC), rem = i % (HN * HC);
    z[b * HE * HC + rem] = 0.f;                  // window part written by edge
    h2[i] = 0.f;
}

// -------- fused edge kernel: kNN scatter + window means (atomics) ---------
__global__ __launch_bounds__(256) void hg19_edge(const unsigned int* pairs, const int* Dv,
                                                 const float* y, float* z) {
    int wv = (blockIdx.x * 256 + threadIdx.x) >> 6;
    int lane = threadIdx.x & 63;
    if (wv < NPAIRS) {
        unsigned int pk = pairs[wv];
        int b = pk >> 24;
        if (b >= HB) return;                     // defensive (poison)
        int p = (pk >> 12) & 0xFFF, m = pk & 0xFFF;
        float invde = 1.f / (float)max(Dv[b * HN + p], 1);
        atomicAdd(&z[(b * HE + p) * HC + lane], y[(b * HN + m) * HC + lane] * invde);
    } else {
        int w2 = wv - NPAIRS;
        if (w2 >= HB * HE2) return;
        int b = w2 / HE2, w = w2 % HE2;
        int wr = w / HW, wc = w % HW;
        float acc = 0.f;
        #pragma unroll
        for (int i = 0; i < 5; i++)
            #pragma unroll
            for (int j = 0; j < 5; j++)
                acc += y[(b * HN + (wr * 2 + i) * HL + wc * 2 + j) * HC + lane];
        z[(b * HE + HN + w) * HC + lane] = acc * (1.f / 25.f);
    }
}

// -------- h2[m] += z[p] over the pair list (atomic) -----------------------
__global__ __launch_bounds__(256) void hg19_gscatter(const unsigned int* pairs,
                                                     const float* z, float* h2) {
    int idx = (blockIdx.x * 256 + threadIdx.x) >> 6;
    int lane = threadIdx.x & 63;
    if (idx >= NPAIRS) return;
    unsigned int pk = pairs[idx];
    int b = pk >> 24;
    if (b >= HB) return;                         // defensive (poison)
    int p = (pk >> 12) & 0xFFF, m = pk & 0xFFF;
    atomicAdd(&h2[(b * HN + m) * HC + lane], z[(b * HE + p) * HC + lane]);
}

// -------- add window contributions + final Dv^-1/2 scale ------------------
__global__ __launch_bounds__(256) void hg19_gfinish(const float* z, const int* indeg, float* h2) {
    int wave = (blockIdx.x * 256 + threadIdx.x) >> 6;  // one wave per (b, node)
    int lane = threadIdx.x & 63;
    int b = wave / HN, n = wave % HN;
    int g = b * HN + n;
    float acc = h2[g * HC + lane];
    int r = n / HL, c = n % HL;
    int rlo = hg19_lo(r), rhi = hg19_hi(r), clo = hg19_lo(c), chi = hg19_hi(c);
    for (int wr = rlo; wr <= rhi; wr++)
        for (int wc = clo; wc <= chi; wc++)
            acc += z[(b * HE + HN + wr * HW + wc) * HC + lane];
    int dvn = max(indeg[g] + max(0, rhi - rlo + 1) * max(0, chi - clo + 1), 1);
    h2[g * HC + lane] = acc * rsqrtf((float)dvn);
}

// -------- BN stats --------------------------------------------------------
__global__ __launch_bounds__(256) void hg19_bnstats(const float* h2, float* bnsum, float* bnss) {
    int t = threadIdx.x;
    int c = t & 63, rg = t >> 6;
    int row0 = blockIdx.x * 36;      // 256 blocks * 36 rows = 9216
    float s = 0.f, ss = 0.f;
    for (int r = rg; r < 36; r += 4) {
        float v = h2[(row0 + r) * HC + c];
        s += v; ss += v * v;
    }
    __shared__ float ls[256], lss[256];
    ls[t] = s; lss[t] = ss;
    __syncthreads();
    if (t < 64) {
        s  = ls[t]  + ls[t + 64]  + ls[t + 128]  + ls[t + 192];
        ss = lss[t] + lss[t + 64] + lss[t + 128] + lss[t + 192];
        atomicAdd(&bnsum[t], s);
        atomicAdd(&bnss[t], ss);
    }
}

// -------- BN + ReLU + residual --------------------------------------------
__global__ __launch_bounds__(256) void hg19_final(const float* h2, const float* x,
                                                  const float* gamma, const float* beta,
                                                  const float* bnsum, const float* bnss,
                                                  float* out) {
    int i = blockIdx.x * 256 + threadIdx.x;
    int c = i & 63;
    const float M = (float)(HB * HN);
    float mean = bnsum[c] / M;
    float var  = bnss[c] / M - mean * mean;
    float inv  = rsqrtf(var + 1e-5f);
    float h = gamma[c] * (h2[i] - mean) * inv + beta[c];
    out[i] = fmaxf(h, 0.f) + x[i];
}

extern "C" void kernel_launch(void* const* d_in, const int* in_sizes, int n_in,
                              void* d_out, int out_size, void* d_ws, size_t ws_size,
                              hipStream_t stream) {
    const float* x     = (const float*)d_in[0];
    const float* W     = (const float*)d_in[1];
    const float* bias  = (const float*)d_in[2];
    const float* gamma = (const float*)d_in[3];
    const float* beta  = (const float*)d_in[4];
    float* out = (float*)d_out;
    (void)in_sizes; (void)n_in;

    char* ws = (char*)d_ws;
    size_t off = 0;
    float*              xsq    = (float*)(ws + off);              off += (size_t)HB * HN * 4;
    float*              h1     = (float*)(ws + off);              off += (size_t)HB * HN * HC * 4;
    float*              h2     = (float*)(ws + off);              off += (size_t)HB * HN * HC * 4;
    int*                Dv     = (int*)(ws + off);                off += (size_t)HB * HN * 4;
    int*                indeg  = (int*)(ws + off);                off += (size_t)HB * HN * 4;
    int*                offs   = (int*)(ws + off);                off += (size_t)HB * HN * 4;
    int*                needfb = (int*)(ws + off);                off += (size_t)HB * HN * 4;
    unsigned int*       pairs  = (unsigned int*)(ws + off);       off += (size_t)NPAIRS * 4;
    float*              bnsum  = (float*)(ws + off);              off += 256;
    float*              bnss   = (float*)(ws + off);              off += 256;
    unsigned long long* topc   = (unsigned long long*)(ws + off); off += (size_t)HB * HN * HCAP8 * 8;
    float*              xT     = (float*)(ws + off);              // z aliases xT
    float*              z      = (float*)(ws + off);
    off += (size_t)HB * HE * HC * 4;   // max(xT, z) = z

    if (ws_size < off) {
        hg19_sentinel<<<(out_size + 255) / 256, 256, 0, stream>>>(out, out_size);
        return;
    }

    const int EDGE_WAVES = NPAIRS + HB * HE2;    // 103312, divisible by 4

    hg19_init<<<(HB * HN + 255) / 256, 256, 0, stream>>>(Dv, indeg, needfb, bnsum, bnss);
    hg19_linear<<<HB * HN / 4, 256, 0, stream>>>(x, W, bias, h1, xsq, xT);
    hg19_knn_count<<<HB * (HN / HRPB), 256, 0, stream>>>(xT, xsq, Dv, topc);
    hg19_scan<<<1, 256, 0, stream>>>(Dv, offs);
    hg19_sel_top<<<HB * (HN / HRPB), 256, 0, stream>>>(topc, Dv, offs, needfb, indeg, pairs);
    hg19_sel_fullfb<<<HB * (HN / HRPB), 256, 0, stream>>>(xT, xsq, Dv, offs, needfb, indeg, pairs);
    hg19_prep<<<(HB * HN * HC) / 256, 256, 0, stream>>>(h1, indeg, z, h2);
    hg19_edge<<<EDGE_WAVES / 4, 256, 0, stream>>>(pairs, Dv, h1, z);
    hg19_gscatter<<<(NPAIRS * 64) / 256, 256, 0, stream>>>(pairs, z, h2);
    hg19_gfinish<<<(HB * HN) / 4, 256, 0, stream>>>(z, indeg, h2);
    hg19_bnstats<<<256, 256, 0, stream>>>(h2, bnsum, bnss);
    hg19_final<<<(HB * HN * HC) / 256, 256, 0, stream>>>(h2, x, gamma, beta, bnsum, bnss, out);
}